// Round 4
// baseline (126.614 us; speedup 1.0000x reference)
//
#include <hip/hip_runtime.h>
#include <hip/hip_bf16.h>
#include <stdint.h>

// MLP: hidden = X @ W1^T + b1 ; out = hidden @ W2^T + b2
// X [16384,2048] f32, W1 [512,2048], b1 [512], W2 [2048,512], b2 [2048]
// R7: normalize by block-steps: gemm2 = ~1125 cy/step (32 KB staged, pure
// global_load_lds); gemm1 = ~3450 cy/step (48 KB, reg-staged X). The X
// reg-staging (global->VGPR->cvt->ds_write) keeps X latency + LDS-write in
// the barrier-locked critical section. Fix: gemm1 becomes a gemm2 clone:
//  - X staged as RAW F32 via global_load_lds (8 instrs/thread/step),
//    16-unit XOR swizzle via pre-swizzled global source (rule #21)
//  - f32->bf16 on the LDS->fragment READ path (2x ds_read_b128 + 4 cvt_pk)
//  - 256 thr, 4 waves 2x2 of 64x64 (acc 4x4) -- halves A-LDS-read volume
//  - single-buffered 48 KB, gemm2's exact 2-barrier loop, no setprio
// GEMM2 and weight-cast unchanged.

typedef short bf16x8 __attribute__((ext_vector_type(8)));
typedef float f32x4 __attribute__((ext_vector_type(4)));

static __device__ __forceinline__ unsigned short f32_to_bf16_rne(float f) {
    unsigned int u = __float_as_uint(f);
    u += 0x7fffu + ((u >> 16) & 1u);
    return (unsigned short)(u >> 16);
}

static __device__ __forceinline__ unsigned int cvt_pk_bf16(float lo, float hi) {
    unsigned int r;
    asm("v_cvt_pk_bf16_f32 %0, %1, %2" : "=v"(r) : "v"(lo), "v"(hi));
    return r;  // low 16 = bf16(lo), high 16 = bf16(hi)
}

// one kernel casts both weight matrices (same element count each)
__global__ void cast_weights_bf16(const float* __restrict__ w1,
                                  unsigned short* __restrict__ o1,
                                  const float* __restrict__ w2,
                                  unsigned short* __restrict__ o2, int n4each) {
    int stride = gridDim.x * blockDim.x;
    for (int i = blockIdx.x * blockDim.x + threadIdx.x; i < 2 * n4each;
         i += stride) {
        const float* in = (i < n4each) ? w1 : w2;
        unsigned short* out = (i < n4each) ? o1 : o2;
        int j = (i < n4each) ? i : i - n4each;
        float4 v = ((const float4*)in)[j];
        ushort4 o;
        o.x = f32_to_bf16_rne(v.x);
        o.y = f32_to_bf16_rne(v.y);
        o.z = f32_to_bf16_rne(v.z);
        o.w = f32_to_bf16_rne(v.w);
        ((ushort4*)out)[j] = o;
    }
}

#define GLOAD_LDS16(gsrc, ldst)                                              \
    __builtin_amdgcn_global_load_lds(                                        \
        (const __attribute__((address_space(1))) void*)(gsrc),               \
        (__attribute__((address_space(3))) void*)(ldst), 16, 0, 0)

// ---------------------------------------------------------------------------
// GEMM1: H[16384][512] bf16 = X[16384][2048] f32 @ W1bf[512][2048]^T + b1
// 128x128 tile, 256 thr (2x2 waves of 64x64), BK=64, single-buffered 48 KB.
// grid = 512 blocks (2/CU), chunked XCD swizzle.
// X in LDS as f32 [128][64]: rows 256 B = 16 units of 16 B,
//   phys_unit = logical ^ (row&15); staged via global_load_lds with
//   pre-swizzled source column; converted to bf16 on fragment read.
// W in LDS as bf16 [128][64]: rows 128 B = 8 units, phys = logical ^ (row&7).
// ---------------------------------------------------------------------------
__global__ __launch_bounds__(256, 2)
void gemm1_xcast(const float* __restrict__ X,
                 const unsigned short* __restrict__ W1,
                 const float* __restrict__ b1,
                 unsigned short* __restrict__ H) {
    constexpr int K = 2048, N = 512, BK = 64, NSTEP = K / BK;  // 32 steps

    __shared__ __align__(16) float ldsX[128 * BK];           // 32 KB (f32!)
    __shared__ __align__(16) unsigned short ldsW[128 * BK];  // 16 KB

    const int tid  = threadIdx.x;
    const int lane = tid & 63;
    const int wid  = tid >> 6;   // 0..3
    const int wr   = wid >> 1;   // 0..1 : 64-row half
    const int wc   = wid & 1;    // 0..1 : 64-col half

    // chunked XCD swizzle: nwg = 512 = 8 * 64 -> XCD x gets logical [64x,64x+64)
    const int bid = blockIdx.x;
    const int swz = ((bid & 7) << 6) + (bid >> 3);
    const int bm  = swz >> 2;            // 4 col-blocks of a row-panel adjacent
    const int bn  = swz & 3;
    const int brow = bm << 7;
    const int bcol = bn << 7;

    const int lrow = lane & 15;
    const int ku   = lane >> 4;

    // X staging: instr i (0..7): thread t -> row i*16 + (t>>4), phys unit t&15;
    // source column = (phys ^ (row&15)) = (t&15) ^ (t>>4)  (row&15 == t>>4)
    const int xr  = tid >> 4;            // 0..15
    const int xsw = ((tid & 15) ^ xr) << 4;  // pre-swizzled byte col
    const char* xsrc0 = (const char*)(X + (size_t)(brow + xr) * K) + xsw;

    // W staging: instr i (0..3): thread t -> row i*32 + (t>>3), unit t&7;
    // source column = ((t&7) ^ (row&7)) ; row&7 == (t>>3)&7
    const int wrr = tid >> 3;            // 0..31
    const int wsw = ((tid & 7) ^ (wrr & 7)) << 4;
    const char* wsrc0 = (const char*)(W1 + (size_t)(bcol + wrr) * K) + wsw;

    f32x4 acc[4][4] = {};

    auto stage = [&](int k0) {
#pragma unroll
        for (int i = 0; i < 8; ++i)
            GLOAD_LDS16(xsrc0 + ((size_t)i * 16 * K + k0) * 4,
                        (char*)ldsX + i * 4096 + tid * 16);
#pragma unroll
        for (int i = 0; i < 4; ++i)
            GLOAD_LDS16(wsrc0 + ((size_t)i * 32 * K + k0) * 2,
                        (char*)ldsW + i * 4096 + tid * 16);
    };

    auto compute = [&]() {
#pragma unroll
        for (int kk = 0; kk < 2; ++kk) {
            const int luA = (ku + (kk << 2)) << 1;   // logical 16B unit (of 16)
            const int unW = ((ku + (kk << 2)) ^ (lrow & 7)) << 4;
            bf16x8 a[4], b[4];
#pragma unroll
            for (int m = 0; m < 4; ++m) {
                const int ra = (wr << 6) + (m << 4) + lrow;  // ra&15 == lrow
                const char* base = (const char*)ldsX + ra * 256;
                f32x4 lo = *(const f32x4*)(base + ((luA ^ lrow) << 4));
                f32x4 hi = *(const f32x4*)(base + (((luA + 1) ^ lrow) << 4));
                uint4 u;
                u.x = cvt_pk_bf16(lo[0], lo[1]);
                u.y = cvt_pk_bf16(lo[2], lo[3]);
                u.z = cvt_pk_bf16(hi[0], hi[1]);
                u.w = cvt_pk_bf16(hi[2], hi[3]);
                a[m] = *(const bf16x8*)&u;
            }
#pragma unroll
            for (int n = 0; n < 4; ++n)
                b[n] = *(const bf16x8*)((const char*)ldsW +
                       ((wc << 6) + (n << 4) + lrow) * 128 + unW);
#pragma unroll
            for (int m = 0; m < 4; ++m)
#pragma unroll
                for (int n = 0; n < 4; ++n)
                    acc[m][n] = __builtin_amdgcn_mfma_f32_16x16x32_bf16(
                        a[m], b[n], acc[m][n], 0, 0, 0);
        }
    };

    stage(0);
    __syncthreads();

    for (int t = 0; t < NSTEP; ++t) {
        compute();
        if (t + 1 < NSTEP) {
            __syncthreads();
            stage((t + 1) * BK);
            __syncthreads();
        }
    }

    // epilogue: C/D layout col = lane&15, row = (lane>>4)*4 + j  [m89]
    const int r0 = (lane >> 4) << 2;
#pragma unroll
    for (int n = 0; n < 4; ++n) {
        const int col = bcol + (wc << 6) + (n << 4) + lrow;
        const float bb = b1[col];
#pragma unroll
        for (int m = 0; m < 4; ++m)
#pragma unroll
            for (int j = 0; j < 4; ++j) {
                const int row = brow + (wr << 6) + (m << 4) + r0 + j;
                H[(size_t)row * N + col] = f32_to_bf16_rne(acc[m][n][j] + bb);
            }
    }
}

// ---------------------------------------------------------------------------
// GEMM2: out[16384][2048] f32 = Hbf[16384][512] @ W2bf[2048][512]^T + b2
// 128x128 tile, 256 thr, BK=64, single-buffered 32 KB -> 5 blocks/CU.
// grid = 128*16 = 2048 blocks, chunked XCD swizzle (q=256). (unchanged)
// ---------------------------------------------------------------------------
__global__ __launch_bounds__(256)
void gemm2(const unsigned short* __restrict__ A,
           const unsigned short* __restrict__ Bt,
           const float* __restrict__ bias,
           float* __restrict__ C) {
    constexpr int N = 2048, Kd = 512, BK = 64, NSTEP = Kd / BK;  // 8 steps

    __shared__ __align__(16) unsigned short ldsA[128 * BK];  // 16 KB
    __shared__ __align__(16) unsigned short ldsB[128 * BK];  // 16 KB

    const int tid  = threadIdx.x;
    const int lane = tid & 63;
    const int wid  = tid >> 6;
    const int wr   = wid >> 1;
    const int wc   = wid & 1;

    const int bid = blockIdx.x;
    const int swz = ((bid & 7) << 8) + (bid >> 3);   // nwg=2048, q=256
    const int bn  = swz & 15;
    const int bm  = swz >> 4;
    const int brow = bm << 7;
    const int bcol = bn << 7;

    const int lrow = lane & 15;
    const int ku   = lane >> 4;
    const int rx   = lrow & 7;

    const int srow = tid >> 3;
    const int sgu  = (tid & 7) ^ (srow & 7);

    f32x4 acc[4][4] = {};

    auto stage = [&](int k0) {
#pragma unroll
        for (int i = 0; i < 4; ++i) {
            const int row = i * 32 + srow;
            const char* sa =
                (const char*)(A + (size_t)(brow + row) * Kd + k0) + (sgu << 4);
            const char* sb =
                (const char*)(Bt + (size_t)(bcol + row) * Kd + k0) + (sgu << 4);
            GLOAD_LDS16(sa, (char*)ldsA + i * 4096 + tid * 16);
            GLOAD_LDS16(sb, (char*)ldsB + i * 4096 + tid * 16);
        }
    };
    auto compute = [&]() {
#pragma unroll
        for (int kk = 0; kk < 2; ++kk) {
            const int un = ((ku + (kk << 2)) ^ rx) << 4;
            bf16x8 a[4], b[4];
#pragma unroll
            for (int m = 0; m < 4; ++m)
                a[m] = *(const bf16x8*)((const char*)ldsA +
                       ((wr << 6) + (m << 4) + lrow) * 128 + un);
#pragma unroll
            for (int n = 0; n < 4; ++n)
                b[n] = *(const bf16x8*)((const char*)ldsB +
                       ((wc << 6) + (n << 4) + lrow) * 128 + un);
#pragma unroll
            for (int m = 0; m < 4; ++m)
#pragma unroll
                for (int n = 0; n < 4; ++n)
                    acc[m][n] = __builtin_amdgcn_mfma_f32_16x16x32_bf16(
                        a[m], b[n], acc[m][n], 0, 0, 0);
        }
    };

    stage(0);
    __syncthreads();

    for (int t = 0; t < NSTEP; ++t) {
        compute();
        if (t + 1 < NSTEP) {
            __syncthreads();
            stage((t + 1) * BK);
            __syncthreads();
        }
    }

    const int r0 = (lane >> 4) << 2;
#pragma unroll
    for (int n = 0; n < 4; ++n) {
        const int col = bcol + (wc << 6) + (n << 4) + lrow;
        const float bb = bias[col];
#pragma unroll
        for (int m = 0; m < 4; ++m)
#pragma unroll
            for (int j = 0; j < 4; ++j) {
                const int row = brow + (wr << 6) + (m << 4) + r0 + j;
                C[(size_t)row * N + col] = acc[m][n][j] + bb;
            }
    }
}

extern "C" void kernel_launch(void* const* d_in, const int* in_sizes, int n_in,
                              void* d_out, int out_size, void* d_ws, size_t ws_size,
                              hipStream_t stream) {
    const float* X  = (const float*)d_in[0];   // [16384][2048]
    const float* W1 = (const float*)d_in[1];   // [512][2048]
    const float* b1 = (const float*)d_in[2];   // [512]
    const float* W2 = (const float*)d_in[3];   // [2048][512]
    const float* b2 = (const float*)d_in[4];   // [2048]

    const int B = 16384, M = 2048, Kd = 512;

    // workspace: W1bf (2MB), W2bf (2MB), Hbf (16.8MB)
    char* ws = (char*)d_ws;
    unsigned short* W1bf = (unsigned short*)ws;
    unsigned short* W2bf = W1bf + (size_t)Kd * M;
    unsigned short* Hbf  = W2bf + (size_t)M * Kd;

    // both weight casts in one launch: 2 * 256K float4s, one per thread
    cast_weights_bf16<<<2048, 256, 0, stream>>>(W1, W1bf, W2, W2bf,
                                                Kd * M / 4);

    gemm1_xcast<<<(B / 128) * (Kd / 128), 256, 0, stream>>>(X, W1bf, b1, Hbf);
    gemm2<<<(B / 128) * (M / 128), 256, 0, stream>>>(Hbf, W2bf, b2,
                                                     (float*)d_out);
}